// Round 1
// baseline (52056.171 us; speedup 1.0000x reference)
//
#include <hip/hip_runtime.h>
#include <cstdint>
#include <cstddef>

#define T_STEPS 2048
#define BATCH   32
#define VDIM    512
#define HDIM    512

// ---------------- Phase 1: x-projection GEMM ----------------
// xp[g][m][n] = X[m][:V] @ Wg[0:V][n] + bg[n],  g in {0:reset, 1:net, 2:update}
// X: [M, V] row-major (chunk of inputs), Wg: [(V+H), H] row-major, xp: [3][M][H]
__global__ __launch_bounds__(256)
void xproj_gemm(const float* __restrict__ X,
                const float* __restrict__ W0, const float* __restrict__ b0,
                const float* __restrict__ W1, const float* __restrict__ b1,
                const float* __restrict__ W2, const float* __restrict__ b2,
                float* __restrict__ xp, int M)
{
    const int g = blockIdx.z;
    const float* W    = (g == 0) ? W0 : (g == 1) ? W1 : W2;
    const float* bias = (g == 0) ? b0 : (g == 1) ? b1 : b2;
    float* out = xp + (size_t)g * M * HDIM;

    __shared__ float As[16][68];   // A^T tile: As[kk][m], padded
    __shared__ float Bs[16][64];   // B tile:   Bs[kk][n]

    const int tid = threadIdx.x;
    const int tx = tid & 15;       // 0..15 -> 4 output cols each
    const int ty = tid >> 4;       // 0..15 -> 4 output rows each
    const int row0 = blockIdx.y * 64;
    const int n0   = blockIdx.x * 64;

    // staging assignments
    const int lm = tid >> 2;        // 0..63  (A row within tile)
    const int lk = (tid & 3) * 4;   // 0,4,8,12 (A k-quad)
    const int bk = tid >> 4;        // 0..15  (B k row)
    const int bn = (tid & 15) * 4;  // B col quad

    float acc[4][4] = {};

    for (int k0 = 0; k0 < VDIM; k0 += 16) {
        float4 av = *(const float4*)&X[(size_t)(row0 + lm) * VDIM + k0 + lk];
        float4 bv = *(const float4*)&W[(size_t)(k0 + bk) * HDIM + n0 + bn];
        __syncthreads();           // previous iteration's reads complete
        As[lk + 0][lm] = av.x;
        As[lk + 1][lm] = av.y;
        As[lk + 2][lm] = av.z;
        As[lk + 3][lm] = av.w;
        *(float4*)&Bs[bk][bn] = bv;
        __syncthreads();
        #pragma unroll
        for (int kk = 0; kk < 16; ++kk) {
            float4 a = *(const float4*)&As[kk][ty * 4];
            float4 b = *(const float4*)&Bs[kk][tx * 4];
            float ar[4] = {a.x, a.y, a.z, a.w};
            float br[4] = {b.x, b.y, b.z, b.w};
            #pragma unroll
            for (int i = 0; i < 4; ++i)
                #pragma unroll
                for (int j = 0; j < 4; ++j)
                    acc[i][j] += ar[i] * br[j];
        }
    }

    float4 bb = *(const float4*)&bias[n0 + tx * 4];
    #pragma unroll
    for (int i = 0; i < 4; ++i) {
        const int row = row0 + ty * 4 + i;
        float4 o;
        o.x = acc[i][0] + bb.x;
        o.y = acc[i][1] + bb.y;
        o.z = acc[i][2] + bb.z;
        o.w = acc[i][3] + bb.w;
        *(float4*)&out[(size_t)row * HDIM + n0 + tx * 4] = o;
    }
}

// ---------------- Phase 2: sequential GRU scan ----------------
// One workgroup per batch element; 512 threads = one output column each.
// xp: [3][M][H] chunk-local x-projections (bias included), M = nt*BATCH.
// Wrh/Wnh/Wzh point at the h-part rows (W + V*H).
__global__ __launch_bounds__(512)
void gru_scan(const float* __restrict__ xp,
              const float* __restrict__ Wrh,
              const float* __restrict__ Wnh,
              const float* __restrict__ Wzh,
              const float* __restrict__ state,
              float* __restrict__ out,
              int t0, int nt, int M)
{
    const int b = blockIdx.x;
    const int n = threadIdx.x;

    __shared__ float hs[HDIM];
    __shared__ float us[HDIM];

    float* hcarry = out + (size_t)T_STEPS * BATCH * HDIM + (size_t)b * HDIM;

    hs[n] = (t0 == 0) ? state[(size_t)b * HDIM + n] : hcarry[n];
    __syncthreads();

    const size_t gstride = (size_t)M * HDIM;
    float hn = hs[n];

    for (int tt = 0; tt < nt; ++tt) {
        const size_t rowoff = ((size_t)tt * BATCH + b) * HDIM + n;

        // ---- R gate: accR = h . Wrh[:, n] ----
        float accR = 0.f;
        #pragma unroll 16
        for (int k = 0; k < HDIM; ++k)
            accR += hs[k] * Wrh[(size_t)k * HDIM + n];
        const float xr = xp[rowoff];
        const float R = 1.f / (1.f + __expf(-(xr + accR)));
        us[n] = hs[n] * R;
        __syncthreads();   // us complete; all hs reads of this step done

        // ---- candidate + update gates from u = h*R ----
        float accN = 0.f, accZ = 0.f;
        #pragma unroll 8
        for (int k = 0; k < HDIM; ++k) {
            const float u = us[k];
            accN += u * Wnh[(size_t)k * HDIM + n];
            accZ += u * Wzh[(size_t)k * HDIM + n];
        }
        const float xn = xp[gstride + rowoff];
        const float xz = xp[2 * gstride + rowoff];
        const float Hc = tanhf(xn + accN);
        const float Z  = 1.f / (1.f + __expf(-(xz + accZ)));
        hn = Z * hs[n] + (1.f - Z) * Hc;

        out[((size_t)(t0 + tt) * BATCH + b) * HDIM + n] = hn;
        __syncthreads();   // everyone finished reading us before hs update
        hs[n] = hn;
        __syncthreads();   // hs visible for next step's accR
    }

    hcarry[n] = hn;        // persist h across chunk launches; final chunk = h_final
}

extern "C" void kernel_launch(void* const* d_in, const int* in_sizes, int n_in,
                              void* d_out, int out_size, void* d_ws, size_t ws_size,
                              hipStream_t stream) {
    const float* inputs   = (const float*)d_in[0];
    const float* state    = (const float*)d_in[1];
    const float* W_reset  = (const float*)d_in[2];
    const float* b_reset  = (const float*)d_in[3];
    const float* W_net    = (const float*)d_in[4];
    const float* b_net    = (const float*)d_in[5];
    const float* W_update = (const float*)d_in[6];
    const float* b_update = (const float*)d_in[7];
    float* out = (float*)d_out;
    float* xp  = (float*)d_ws;

    // chunk size over T, limited by workspace: xp needs 3*C*B*H*4 bytes
    const size_t per_t = 3ull * BATCH * HDIM * sizeof(float);
    int C = (int)(ws_size / per_t);
    if (C > 256) C = 256;   // keep xp chunk L3-resident
    C &= ~1;                // even -> M divisible by 64
    if (C < 2) C = 2;

    for (int t0 = 0; t0 < T_STEPS; t0 += C) {
        const int nt = (T_STEPS - t0 < C) ? (T_STEPS - t0) : C;
        const int M  = nt * BATCH;

        dim3 g1(HDIM / 64, M / 64, 3);
        xproj_gemm<<<g1, 256, 0, stream>>>(inputs + (size_t)t0 * BATCH * VDIM,
                                           W_reset, b_reset,
                                           W_net,   b_net,
                                           W_update, b_update,
                                           xp, M);

        gru_scan<<<BATCH, HDIM, 0, stream>>>(xp,
                                             W_reset  + (size_t)VDIM * HDIM,
                                             W_net    + (size_t)VDIM * HDIM,
                                             W_update + (size_t)VDIM * HDIM,
                                             state, out, t0, nt, M);
    }
}

// Round 2
// 28111.588 us; speedup vs baseline: 1.8518x; 1.8518x over previous
//
#include <hip/hip_runtime.h>
#include <cstdint>
#include <cstddef>

#define T_STEPS 2048
#define BATCH   32
#define VDIM    512
#define HDIM    512
#define SLICES  8      // WGs per batch element
#define COLS    64     // output columns per WG
#define KPT     64     // k-range per thread (HDIM / SLICES)
#define FSTRIDE 16     // u32 per flag slot (64 B, own cacheline-ish)

// ---------------- Phase 1: x-projection GEMM (unchanged, ~1.1 ms total) ----
// xp[g][m][n] = X[m][:V] @ Wg[0:V][n] + bg[n]
__global__ __launch_bounds__(256)
void xproj_gemm(const float* __restrict__ X,
                const float* __restrict__ W0, const float* __restrict__ b0,
                const float* __restrict__ W1, const float* __restrict__ b1,
                const float* __restrict__ W2, const float* __restrict__ b2,
                float* __restrict__ xp, int M)
{
    const int g = blockIdx.z;
    const float* W    = (g == 0) ? W0 : (g == 1) ? W1 : W2;
    const float* bias = (g == 0) ? b0 : (g == 1) ? b1 : b2;
    float* out = xp + (size_t)g * M * HDIM;

    __shared__ float As[16][68];
    __shared__ float Bs[16][64];

    const int tid = threadIdx.x;
    const int tx = tid & 15;
    const int ty = tid >> 4;
    const int row0 = blockIdx.y * 64;
    const int n0   = blockIdx.x * 64;

    const int lm = tid >> 2;
    const int lk = (tid & 3) * 4;
    const int bk = tid >> 4;
    const int bn = (tid & 15) * 4;

    float acc[4][4] = {};

    for (int k0 = 0; k0 < VDIM; k0 += 16) {
        float4 av = *(const float4*)&X[(size_t)(row0 + lm) * VDIM + k0 + lk];
        float4 bv = *(const float4*)&W[(size_t)(k0 + bk) * HDIM + n0 + bn];
        __syncthreads();
        As[lk + 0][lm] = av.x;
        As[lk + 1][lm] = av.y;
        As[lk + 2][lm] = av.z;
        As[lk + 3][lm] = av.w;
        *(float4*)&Bs[bk][bn] = bv;
        __syncthreads();
        #pragma unroll
        for (int kk = 0; kk < 16; ++kk) {
            float4 a = *(const float4*)&As[kk][ty * 4];
            float4 b = *(const float4*)&Bs[kk][tx * 4];
            float ar[4] = {a.x, a.y, a.z, a.w};
            float br[4] = {b.x, b.y, b.z, b.w};
            #pragma unroll
            for (int i = 0; i < 4; ++i)
                #pragma unroll
                for (int j = 0; j < 4; ++j)
                    acc[i][j] += ar[i] * br[j];
        }
    }

    float4 bb = *(const float4*)&bias[n0 + tx * 4];
    #pragma unroll
    for (int i = 0; i < 4; ++i) {
        const int row = row0 + ty * 4 + i;
        float4 o;
        o.x = acc[i][0] + bb.x;
        o.y = acc[i][1] + bb.y;
        o.z = acc[i][2] + bb.z;
        o.w = acc[i][3] + bb.w;
        *(float4*)&out[(size_t)row * HDIM + n0 + tx * 4] = o;
    }
}

// ---------------- Phase 2: scan with register-resident weights ----------------
// Grid: 256 WGs; blockIdx = b + 32*s  (batch b, column slice s of 64 cols).
// Block: 512 threads; thread = (c = tid&63 -> column, j = tid>>6 -> k-group).
// Weights for (col, k-range) live in 192 VGPRs, loaded once per launch -> zero
// per-step weight traffic. Cross-WG exchange of u and h via ws buffers with
// agent-scope release/acquire flags (per-batch, 8-WG fan-in).
__global__ __launch_bounds__(512, 2)
void gru_scan2(const float* __restrict__ xp,
               const float* __restrict__ Wrh, const float* __restrict__ Wnh,
               const float* __restrict__ Wzh,
               const float* __restrict__ state, float* __restrict__ out,
               float* __restrict__ hbuf, float* __restrict__ ubuf,
               unsigned* __restrict__ hflag, unsigned* __restrict__ uflag,
               int t0, int nt, int M)
{
    const int b   = blockIdx.x & (BATCH - 1);
    const int s   = blockIdx.x >> 5;
    const int tid = threadIdx.x;
    const int c   = tid & (COLS - 1);
    const int j   = tid >> 6;

    __shared__ float hlds[HDIM];
    __shared__ float ulds[HDIM];
    __shared__ float redR[SLICES][COLS];
    __shared__ float redN[SLICES][COLS];
    __shared__ float redZ[SLICES][COLS];

    // ---- one-time: weights -> registers (3 x 64 fp32 = 192 VGPRs) ----
    float w_r[KPT], w_n[KPT], w_z[KPT];
    {
        const size_t coloff = (size_t)s * COLS + c;
        const float* pr = Wrh + (size_t)j * KPT * HDIM + coloff;
        const float* pn = Wnh + (size_t)j * KPT * HDIM + coloff;
        const float* pz = Wzh + (size_t)j * KPT * HDIM + coloff;
        #pragma unroll
        for (int kk = 0; kk < KPT; ++kk) {
            w_r[kk] = pr[(size_t)kk * HDIM];
            w_n[kk] = pn[(size_t)kk * HDIM];
            w_z[kk] = pz[(size_t)kk * HDIM];
        }
    }

    const int n = s * COLS + c;               // wave0 (tid<64): c == tid
    const float* hsrc0 = state + (size_t)b * HDIM;
    float* hb = hbuf + (size_t)b * HDIM;
    float* ub = ubuf + (size_t)b * HDIM;
    const size_t gs = (size_t)M * HDIM;

    float hc = 0.f;                           // own h_t[n] (wave0 only)

    for (int tt = 0; tt < nt; ++tt) {
        const int t = t0 + tt;

        // prefetch xp early (independent of exchanges)
        float xr = 0.f, xn_ = 0.f, xz = 0.f;
        const size_t rb = ((size_t)tt * BATCH + b) * HDIM;
        if (tid < COLS) {
            xr  = xp[rb + n];
            xn_ = xp[gs + rb + n];
            xz  = xp[2 * gs + rb + n];
        }

        // ---- wait for h_t, stage into LDS ----
        if (t > 0 && tid < SLICES) {
            const unsigned* f = hflag + (size_t)(b * SLICES + tid) * FSTRIDE;
            while (__hip_atomic_load(f, __ATOMIC_ACQUIRE, __HIP_MEMORY_SCOPE_AGENT) < (unsigned)t) {}
        }
        __syncthreads();
        if (tid < HDIM / 4) {
            const float4* src = (const float4*)(t == 0 ? hsrc0 : hb);
            ((float4*)hlds)[tid] = src[tid];
        }
        __syncthreads();

        // ---- R-gate partial: accR = sum_k h[k] * Wr[k][n] over own k-range ----
        {
            const float4* h4 = ((const float4*)hlds) + j * (KPT / 4);
            float a0 = 0.f, a1 = 0.f;
            #pragma unroll
            for (int q = 0; q < KPT / 4; ++q) {
                float4 hv = h4[q];
                a0 = fmaf(hv.x, w_r[4 * q + 0], a0);
                a1 = fmaf(hv.y, w_r[4 * q + 1], a1);
                a0 = fmaf(hv.z, w_r[4 * q + 2], a0);
                a1 = fmaf(hv.w, w_r[4 * q + 3], a1);
            }
            redR[j][c] = a0 + a1;
        }
        __syncthreads();

        // ---- u = h * sigmoid(xr + accR); publish u slice ----
        if (tid < COLS) {
            float sR = 0.f;
            #pragma unroll
            for (int jj = 0; jj < SLICES; ++jj) sR += redR[jj][tid];
            float R = 1.f / (1.f + __expf(-(xr + sR)));
            hc = hlds[n];
            float u = hc * R;
            __hip_atomic_store(&ub[n], u, __ATOMIC_RELAXED, __HIP_MEMORY_SCOPE_AGENT);
        }
        if (tid == 0)
            __hip_atomic_store(uflag + (size_t)(b * SLICES + s) * FSTRIDE, (unsigned)(t + 1),
                               __ATOMIC_RELEASE, __HIP_MEMORY_SCOPE_AGENT);
        if (tid < SLICES) {
            const unsigned* f = uflag + (size_t)(b * SLICES + tid) * FSTRIDE;
            while (__hip_atomic_load(f, __ATOMIC_ACQUIRE, __HIP_MEMORY_SCOPE_AGENT) < (unsigned)(t + 1)) {}
        }
        __syncthreads();
        if (tid < HDIM / 4)
            ((float4*)ulds)[tid] = ((const float4*)ub)[tid];
        __syncthreads();

        // ---- N,Z partials over u ----
        {
            const float4* u4 = ((const float4*)ulds) + j * (KPT / 4);
            float aN0 = 0.f, aN1 = 0.f, aZ0 = 0.f, aZ1 = 0.f;
            #pragma unroll
            for (int q = 0; q < KPT / 4; ++q) {
                float4 uv = u4[q];
                aN0 = fmaf(uv.x, w_n[4 * q + 0], aN0);
                aZ0 = fmaf(uv.x, w_z[4 * q + 0], aZ0);
                aN1 = fmaf(uv.y, w_n[4 * q + 1], aN1);
                aZ1 = fmaf(uv.y, w_z[4 * q + 1], aZ1);
                aN0 = fmaf(uv.z, w_n[4 * q + 2], aN0);
                aZ0 = fmaf(uv.z, w_z[4 * q + 2], aZ0);
                aN1 = fmaf(uv.w, w_n[4 * q + 3], aN1);
                aZ1 = fmaf(uv.w, w_z[4 * q + 3], aZ1);
            }
            redN[j][c] = aN0 + aN1;
            redZ[j][c] = aZ0 + aZ1;
        }
        __syncthreads();

        // ---- h_new = Z*h + (1-Z)*tanh(xn + accN); publish h slice ----
        if (tid < COLS) {
            float sN = 0.f, sZ = 0.f;
            #pragma unroll
            for (int jj = 0; jj < SLICES; ++jj) { sN += redN[jj][tid]; sZ += redZ[jj][tid]; }
            float e  = __expf(2.f * (xn_ + sN));
            float Hc = 1.f - 2.f / (e + 1.f);          // tanh, saturation-safe
            float Z  = 1.f / (1.f + __expf(-(xz + sZ)));
            float hnew = Z * hc + (1.f - Z) * Hc;
            __builtin_nontemporal_store(hnew, out + (size_t)t * BATCH * HDIM + (size_t)b * HDIM + n);
            __hip_atomic_store(&hb[n], hnew, __ATOMIC_RELAXED, __HIP_MEMORY_SCOPE_AGENT);
            if (t == T_STEPS - 1)
                out[(size_t)T_STEPS * BATCH * HDIM + (size_t)b * HDIM + n] = hnew;
        }
        if (tid == 0)
            __hip_atomic_store(hflag + (size_t)(b * SLICES + s) * FSTRIDE, (unsigned)(t + 1),
                               __ATOMIC_RELEASE, __HIP_MEMORY_SCOPE_AGENT);
        // next iteration polls hflag >= t+1
    }
}

extern "C" void kernel_launch(void* const* d_in, const int* in_sizes, int n_in,
                              void* d_out, int out_size, void* d_ws, size_t ws_size,
                              hipStream_t stream) {
    const float* inputs   = (const float*)d_in[0];
    const float* state    = (const float*)d_in[1];
    const float* W_reset  = (const float*)d_in[2];
    const float* b_reset  = (const float*)d_in[3];
    const float* W_net    = (const float*)d_in[4];
    const float* b_net    = (const float*)d_in[5];
    const float* W_update = (const float*)d_in[6];
    const float* b_update = (const float*)d_in[7];
    float* out = (float*)d_out;

    // ws layout: [xp chunk | ... | hbuf | ubuf | hflag | uflag] (tail at end)
    const size_t tail_bytes = (size_t)BATCH * HDIM * 4 * 2
                            + (size_t)BATCH * SLICES * FSTRIDE * 4 * 2; // 128K + 32K
    size_t tail_base = (ws_size - tail_bytes) & ~(size_t)255;
    char* base = (char*)d_ws;
    float*    xp    = (float*)base;
    float*    hbuf  = (float*)(base + tail_base);
    float*    ubuf  = hbuf + (size_t)BATCH * HDIM;
    unsigned* hflag = (unsigned*)(ubuf + (size_t)BATCH * HDIM);
    unsigned* uflag = hflag + (size_t)BATCH * SLICES * FSTRIDE;

    const size_t per_t = 3ull * BATCH * HDIM * sizeof(float);
    int C = (int)(tail_base / per_t);
    if (C > 256) C = 256;
    C &= ~1;
    if (C < 2) C = 2;

    // flags must start at 0 every call (ws is poisoned once, not reset between replays)
    hipMemsetAsync(hflag, 0, (size_t)BATCH * SLICES * FSTRIDE * 4 * 2, stream);

    for (int t0 = 0; t0 < T_STEPS; t0 += C) {
        const int nt = (T_STEPS - t0 < C) ? (T_STEPS - t0) : C;
        const int M  = nt * BATCH;

        dim3 g1(HDIM / 64, M / 64, 3);
        xproj_gemm<<<g1, 256, 0, stream>>>(inputs + (size_t)t0 * BATCH * VDIM,
                                           W_reset, b_reset,
                                           W_net,   b_net,
                                           W_update, b_update,
                                           xp, M);

        gru_scan2<<<BATCH * SLICES, 512, 0, stream>>>(
            xp,
            W_reset  + (size_t)VDIM * HDIM,
            W_net    + (size_t)VDIM * HDIM,
            W_update + (size_t)VDIM * HDIM,
            state, out, hbuf, ubuf, hflag, uflag, t0, nt, M);
    }
}

// Round 3
// 26658.075 us; speedup vs baseline: 1.9527x; 1.0545x over previous
//
#include <hip/hip_runtime.h>
#include <cstdint>
#include <cstddef>

#define T_STEPS 2048
#define BATCH   32
#define VDIM    512
#define HDIM    512
#define SLICES  8      // WGs per batch element
#define COLS    64     // output columns per WG
#define KPT     64     // k-range per thread group (HDIM / SLICES)
#define FSTRIDE 16     // u32 per flag slot (64 B)

// ---------------- Phase 1: x-projection GEMM ----
__global__ __launch_bounds__(256)
void xproj_gemm(const float* __restrict__ X,
                const float* __restrict__ W0, const float* __restrict__ b0,
                const float* __restrict__ W1, const float* __restrict__ b1,
                const float* __restrict__ W2, const float* __restrict__ b2,
                float* __restrict__ xp, int M)
{
    const int g = blockIdx.z;
    const float* W    = (g == 0) ? W0 : (g == 1) ? W1 : W2;
    const float* bias = (g == 0) ? b0 : (g == 1) ? b1 : b2;
    float* out = xp + (size_t)g * M * HDIM;

    __shared__ float As[16][68];
    __shared__ float Bs[16][64];

    const int tid = threadIdx.x;
    const int tx = tid & 15;
    const int ty = tid >> 4;
    const int row0 = blockIdx.y * 64;
    const int n0   = blockIdx.x * 64;

    const int lm = tid >> 2;
    const int lk = (tid & 3) * 4;
    const int bk = tid >> 4;
    const int bn = (tid & 15) * 4;

    float acc[4][4] = {};

    for (int k0 = 0; k0 < VDIM; k0 += 16) {
        float4 av = *(const float4*)&X[(size_t)(row0 + lm) * VDIM + k0 + lk];
        float4 bv = *(const float4*)&W[(size_t)(k0 + bk) * HDIM + n0 + bn];
        __syncthreads();
        As[lk + 0][lm] = av.x;
        As[lk + 1][lm] = av.y;
        As[lk + 2][lm] = av.z;
        As[lk + 3][lm] = av.w;
        *(float4*)&Bs[bk][bn] = bv;
        __syncthreads();
        #pragma unroll
        for (int kk = 0; kk < 16; ++kk) {
            float4 a = *(const float4*)&As[kk][ty * 4];
            float4 b = *(const float4*)&Bs[kk][tx * 4];
            float ar[4] = {a.x, a.y, a.z, a.w};
            float br[4] = {b.x, b.y, b.z, b.w};
            #pragma unroll
            for (int i = 0; i < 4; ++i)
                #pragma unroll
                for (int j = 0; j < 4; ++j)
                    acc[i][j] += ar[i] * br[j];
        }
    }

    float4 bb = *(const float4*)&bias[n0 + tx * 4];
    #pragma unroll
    for (int i = 0; i < 4; ++i) {
        const int row = row0 + ty * 4 + i;
        float4 o;
        o.x = acc[i][0] + bb.x;
        o.y = acc[i][1] + bb.y;
        o.z = acc[i][2] + bb.z;
        o.w = acc[i][3] + bb.w;
        *(float4*)&out[(size_t)row * HDIM + n0 + tx * 4] = o;
    }
}

// ---------------- Phase 2: scan, weights pinned in VGPRs ----------------
// Grid: 256 WGs (batch b = blockIdx&31, slice s = blockIdx>>5), 512 threads.
// 1 WG/CU, 2 waves/SIMD, VGPR budget 256: 192 weight floats pinned via asm.
__global__ __launch_bounds__(512)
__attribute__((amdgpu_waves_per_eu(2, 2)))
void gru_scan2(const float* __restrict__ xp,
               const float* __restrict__ Wrh, const float* __restrict__ Wnh,
               const float* __restrict__ Wzh,
               const float* __restrict__ state, float* __restrict__ out,
               float* __restrict__ hbuf, float* __restrict__ ubuf,
               unsigned* __restrict__ hflag, unsigned* __restrict__ uflag,
               int t0, int nt, int M)
{
    const int b   = blockIdx.x & (BATCH - 1);
    const int s   = blockIdx.x >> 5;
    const int tid = threadIdx.x;
    const int c   = tid & (COLS - 1);
    const int j   = tid >> 6;

    __shared__ float hlds[HDIM];
    __shared__ float ulds[HDIM];
    __shared__ float redR[SLICES][COLS];
    __shared__ float redN[SLICES][COLS];
    __shared__ float redZ[SLICES][COLS];

    // ---- one-time: weights -> registers (3 x 64 fp32 = 192 VGPRs) ----
    float w_r[KPT], w_n[KPT], w_z[KPT];
    {
        const size_t coloff = (size_t)s * COLS + c;
        const float* pr = Wrh + (size_t)j * KPT * HDIM + coloff;
        const float* pn = Wnh + (size_t)j * KPT * HDIM + coloff;
        const float* pz = Wzh + (size_t)j * KPT * HDIM + coloff;
        #pragma unroll
        for (int kk = 0; kk < KPT; ++kk) {
            w_r[kk] = pr[(size_t)kk * HDIM];
            w_n[kk] = pn[(size_t)kk * HDIM];
            w_z[kk] = pz[(size_t)kk * HDIM];
        }
        // pin: opaque def prevents the allocator from rematerializing the
        // loads inside the step loop (round-2 failure mode: VGPR=128, weights
        // re-streamed from L2 every step).
        #pragma unroll
        for (int kk = 0; kk < KPT; ++kk)
            asm volatile("" : "+v"(w_r[kk]), "+v"(w_n[kk]), "+v"(w_z[kk]));
    }

    const int n = s * COLS + c;               // wave0 (tid<64): c == tid
    const float* hsrc0 = state + (size_t)b * HDIM;
    float* hb = hbuf + (size_t)b * HDIM;
    float* ub = ubuf + (size_t)b * HDIM;
    const size_t gs = (size_t)M * HDIM;

    float hc = 0.f;

    for (int tt = 0; tt < nt; ++tt) {
        const int t = t0 + tt;

        // prefetch xp early (independent of the h exchange)
        float xr = 0.f, xn_ = 0.f, xz = 0.f;
        const size_t rb = ((size_t)tt * BATCH + b) * HDIM;
        if (tid < COLS) {
            xr  = xp[rb + n];
            xn_ = xp[gs + rb + n];
            xz  = xp[2 * gs + rb + n];
        }

        // ---- wait for h_t, stage into LDS ----
        if (t > 0 && tid < SLICES) {
            const unsigned* f = hflag + (size_t)(b * SLICES + tid) * FSTRIDE;
            while (__hip_atomic_load(f, __ATOMIC_ACQUIRE, __HIP_MEMORY_SCOPE_AGENT) < (unsigned)t) {}
        }
        __syncthreads();
        if (tid < HDIM / 4) {
            const float4* src = (const float4*)(t == 0 ? hsrc0 : hb);
            ((float4*)hlds)[tid] = src[tid];
        }
        __syncthreads();

        // ---- R-gate partial over own k-range ----
        {
            const float4* h4 = ((const float4*)hlds) + j * (KPT / 4);
            float a0 = 0.f, a1 = 0.f;
            #pragma unroll
            for (int q = 0; q < KPT / 4; ++q) {
                float4 hv = h4[q];
                a0 = fmaf(hv.x, w_r[4 * q + 0], a0);
                a1 = fmaf(hv.y, w_r[4 * q + 1], a1);
                a0 = fmaf(hv.z, w_r[4 * q + 2], a0);
                a1 = fmaf(hv.w, w_r[4 * q + 3], a1);
            }
            redR[j][c] = a0 + a1;
        }
        __syncthreads();

        // ---- u = h * sigmoid(xr + accR); publish u slice ----
        if (tid < COLS) {
            float sR = 0.f;
            #pragma unroll
            for (int jj = 0; jj < SLICES; ++jj) sR += redR[jj][tid];
            float R = 1.f / (1.f + __expf(-(xr + sR)));
            hc = hlds[n];
            float u = hc * R;
            __hip_atomic_store(&ub[n], u, __ATOMIC_RELAXED, __HIP_MEMORY_SCOPE_AGENT);
        }
        if (tid == 0)
            __hip_atomic_store(uflag + (size_t)(b * SLICES + s) * FSTRIDE, (unsigned)(t + 1),
                               __ATOMIC_RELEASE, __HIP_MEMORY_SCOPE_AGENT);
        if (tid < SLICES) {
            const unsigned* f = uflag + (size_t)(b * SLICES + tid) * FSTRIDE;
            while (__hip_atomic_load(f, __ATOMIC_ACQUIRE, __HIP_MEMORY_SCOPE_AGENT) < (unsigned)(t + 1)) {}
        }
        __syncthreads();
        if (tid < HDIM / 4)
            ((float4*)ulds)[tid] = ((const float4*)ub)[tid];
        __syncthreads();

        // ---- N,Z partials over u ----
        {
            const float4* u4 = ((const float4*)ulds) + j * (KPT / 4);
            float aN0 = 0.f, aN1 = 0.f, aZ0 = 0.f, aZ1 = 0.f;
            #pragma unroll
            for (int q = 0; q < KPT / 4; ++q) {
                float4 uv = u4[q];
                aN0 = fmaf(uv.x, w_n[4 * q + 0], aN0);
                aZ0 = fmaf(uv.x, w_z[4 * q + 0], aZ0);
                aN1 = fmaf(uv.y, w_n[4 * q + 1], aN1);
                aZ1 = fmaf(uv.y, w_z[4 * q + 1], aZ1);
                aN0 = fmaf(uv.z, w_n[4 * q + 2], aN0);
                aZ0 = fmaf(uv.z, w_z[4 * q + 2], aZ0);
                aN1 = fmaf(uv.w, w_n[4 * q + 3], aN1);
                aZ1 = fmaf(uv.w, w_z[4 * q + 3], aZ1);
            }
            redN[j][c] = aN0 + aN1;
            redZ[j][c] = aZ0 + aZ1;
        }
        __syncthreads();

        // ---- h_new; publish h slice ----
        if (tid < COLS) {
            float sN = 0.f, sZ = 0.f;
            #pragma unroll
            for (int jj = 0; jj < SLICES; ++jj) { sN += redN[jj][tid]; sZ += redZ[jj][tid]; }
            float e  = __expf(2.f * (xn_ + sN));
            float Hc = 1.f - 2.f / (e + 1.f);          // tanh
            float Z  = 1.f / (1.f + __expf(-(xz + sZ)));
            float hnew = Z * hc + (1.f - Z) * Hc;
            __builtin_nontemporal_store(hnew, out + (size_t)t * BATCH * HDIM + (size_t)b * HDIM + n);
            __hip_atomic_store(&hb[n], hnew, __ATOMIC_RELAXED, __HIP_MEMORY_SCOPE_AGENT);
            if (t == T_STEPS - 1)
                out[(size_t)T_STEPS * BATCH * HDIM + (size_t)b * HDIM + n] = hnew;
        }
        if (tid == 0)
            __hip_atomic_store(hflag + (size_t)(b * SLICES + s) * FSTRIDE, (unsigned)(t + 1),
                               __ATOMIC_RELEASE, __HIP_MEMORY_SCOPE_AGENT);
    }
}

extern "C" void kernel_launch(void* const* d_in, const int* in_sizes, int n_in,
                              void* d_out, int out_size, void* d_ws, size_t ws_size,
                              hipStream_t stream) {
    const float* inputs   = (const float*)d_in[0];
    const float* state    = (const float*)d_in[1];
    const float* W_reset  = (const float*)d_in[2];
    const float* b_reset  = (const float*)d_in[3];
    const float* W_net    = (const float*)d_in[4];
    const float* b_net    = (const float*)d_in[5];
    const float* W_update = (const float*)d_in[6];
    const float* b_update = (const float*)d_in[7];
    float* out = (float*)d_out;

    const size_t tail_bytes = (size_t)BATCH * HDIM * 4 * 2
                            + (size_t)BATCH * SLICES * FSTRIDE * 4 * 2;
    size_t tail_base = (ws_size - tail_bytes) & ~(size_t)255;
    char* base = (char*)d_ws;
    float*    xp    = (float*)base;
    float*    hbuf  = (float*)(base + tail_base);
    float*    ubuf  = hbuf + (size_t)BATCH * HDIM;
    unsigned* hflag = (unsigned*)(ubuf + (size_t)BATCH * HDIM);
    unsigned* uflag = hflag + (size_t)BATCH * SLICES * FSTRIDE;

    const size_t per_t = 3ull * BATCH * HDIM * sizeof(float);
    int C = (int)(tail_base / per_t);
    if (C > T_STEPS) C = T_STEPS;   // single-launch scan if ws allows
    C &= ~1;
    if (C < 2) C = 2;

    // flags must start at 0 every call
    hipMemsetAsync(hflag, 0, (size_t)BATCH * SLICES * FSTRIDE * 4 * 2, stream);

    for (int t0 = 0; t0 < T_STEPS; t0 += C) {
        const int nt = (T_STEPS - t0 < C) ? (T_STEPS - t0) : C;
        const int M  = nt * BATCH;

        dim3 g1(HDIM / 64, M / 64, 3);
        xproj_gemm<<<g1, 256, 0, stream>>>(inputs + (size_t)t0 * BATCH * VDIM,
                                           W_reset, b_reset,
                                           W_net,   b_net,
                                           W_update, b_update,
                                           xp, M);

        gru_scan2<<<BATCH * SLICES, 512, 0, stream>>>(
            xp,
            W_reset  + (size_t)VDIM * HDIM,
            W_net    + (size_t)VDIM * HDIM,
            W_update + (size_t)VDIM * HDIM,
            state, out, hbuf, ubuf, hflag, uflag, t0, nt, M);
    }
}

// Round 4
// 6490.092 us; speedup vs baseline: 8.0209x; 4.1075x over previous
//
#include <hip/hip_runtime.h>
#include <cstdint>
#include <cstddef>

#define T_STEPS 2048
#define BATCH   32
#define VDIM    512
#define HDIM    512
#define SLICES  8      // WGs per batch element
#define COLS    64     // output columns per WG
#define KPT     64     // k-range per wave (HDIM / SLICES)

typedef _Float16 half2v __attribute__((ext_vector_type(2)));
typedef _Float16 half8v __attribute__((ext_vector_type(8)));

__device__ __forceinline__ float dot2h(half2v a, half2v b, float c) {
#if __has_builtin(__builtin_amdgcn_fdot2)
    return __builtin_amdgcn_fdot2(a, b, c, false);
#else
    return fmaf((float)a.x, (float)b.x, fmaf((float)a.y, (float)b.y, c));
#endif
}

__device__ __forceinline__ unsigned long long loadt(const unsigned long long* p) {
    return __hip_atomic_load(p, __ATOMIC_RELAXED, __HIP_MEMORY_SCOPE_AGENT);
}
__device__ __forceinline__ void storet(unsigned long long* p, float v, unsigned tag) {
    unsigned long long x = ((unsigned long long)tag << 32) | (unsigned)__float_as_uint(v);
    __hip_atomic_store(p, x, __ATOMIC_RELAXED, __HIP_MEMORY_SCOPE_AGENT);
}

// ---------------- Phase 1: x-projection GEMM ----
__global__ __launch_bounds__(256)
void xproj_gemm(const float* __restrict__ X,
                const float* __restrict__ W0, const float* __restrict__ b0,
                const float* __restrict__ W1, const float* __restrict__ b1,
                const float* __restrict__ W2, const float* __restrict__ b2,
                float* __restrict__ xp, int M)
{
    const int g = blockIdx.z;
    const float* W    = (g == 0) ? W0 : (g == 1) ? W1 : W2;
    const float* bias = (g == 0) ? b0 : (g == 1) ? b1 : b2;
    float* out = xp + (size_t)g * M * HDIM;

    __shared__ float As[16][68];
    __shared__ float Bs[16][64];

    const int tid = threadIdx.x;
    const int tx = tid & 15;
    const int ty = tid >> 4;
    const int row0 = blockIdx.y * 64;
    const int n0   = blockIdx.x * 64;

    const int lm = tid >> 2;
    const int lk = (tid & 3) * 4;
    const int bk = tid >> 4;
    const int bn = (tid & 15) * 4;

    float acc[4][4] = {};

    for (int k0 = 0; k0 < VDIM; k0 += 16) {
        float4 av = *(const float4*)&X[(size_t)(row0 + lm) * VDIM + k0 + lk];
        float4 bv = *(const float4*)&W[(size_t)(k0 + bk) * HDIM + n0 + bn];
        __syncthreads();
        As[lk + 0][lm] = av.x;
        As[lk + 1][lm] = av.y;
        As[lk + 2][lm] = av.z;
        As[lk + 3][lm] = av.w;
        *(float4*)&Bs[bk][bn] = bv;
        __syncthreads();
        #pragma unroll
        for (int kk = 0; kk < 16; ++kk) {
            float4 a = *(const float4*)&As[kk][ty * 4];
            float4 b = *(const float4*)&Bs[kk][tx * 4];
            float ar[4] = {a.x, a.y, a.z, a.w};
            float br[4] = {b.x, b.y, b.z, b.w};
            #pragma unroll
            for (int i = 0; i < 4; ++i)
                #pragma unroll
                for (int j = 0; j < 4; ++j)
                    acc[i][j] += ar[i] * br[j];
        }
    }

    float4 bb = *(const float4*)&bias[n0 + tx * 4];
    #pragma unroll
    for (int i = 0; i < 4; ++i) {
        const int row = row0 + ty * 4 + i;
        float4 o;
        o.x = acc[i][0] + bb.x;
        o.y = acc[i][1] + bb.y;
        o.z = acc[i][2] + bb.z;
        o.w = acc[i][3] + bb.w;
        *(float4*)&out[(size_t)row * HDIM + n0 + tx * 4] = o;
    }
}

// ---------------- Phase 2: scan, f16x2 weights in VGPRs, tagged exchange ----
// Grid: 256 WGs (b = blockIdx&31, s = blockIdx>>5), 512 threads.
// Wave j (tid>>6) owns k-range [64j, 64j+64): exactly the h/u elements its
// own lanes poll -> staging is wave-local (no barrier). 2 barriers/step.
__global__ __launch_bounds__(512)
__attribute__((amdgpu_waves_per_eu(2, 2)))
void gru_scan3(const float* __restrict__ xp,
               const float* __restrict__ Wrh, const float* __restrict__ Wnh,
               const float* __restrict__ Wzh,
               const float* __restrict__ state, float* __restrict__ out,
               unsigned long long* __restrict__ hT,
               unsigned long long* __restrict__ uT,
               int t0, int nt, int M)
{
    const int b   = blockIdx.x & (BATCH - 1);
    const int s   = blockIdx.x >> 5;
    const int tid = threadIdx.x;
    const int c   = tid & (COLS - 1);
    const int j   = tid >> 6;
    const int n   = s * COLS + c;          // own output column (used by wave 0)

    __shared__ __align__(16) _Float16 hlds[HDIM];
    __shared__ __align__(16) _Float16 ulds[HDIM];
    __shared__ float redR[SLICES][COLS];
    __shared__ float redN[SLICES][COLS];
    __shared__ float redZ[SLICES][COLS];

    // ---- one-time: weights -> f16x2 registers (96 VGPRs) ----
    half2v w2r[KPT / 2], w2n[KPT / 2], w2z[KPT / 2];
    {
        const size_t coloff = (size_t)s * COLS + c;
        const float* pr = Wrh + (size_t)j * KPT * HDIM + coloff;
        const float* pn = Wnh + (size_t)j * KPT * HDIM + coloff;
        const float* pz = Wzh + (size_t)j * KPT * HDIM + coloff;
        #pragma unroll
        for (int q = 0; q < KPT / 2; ++q) {
            half2v r, nn, z;
            r.x  = (_Float16)pr[(size_t)(2 * q) * HDIM];
            r.y  = (_Float16)pr[(size_t)(2 * q + 1) * HDIM];
            nn.x = (_Float16)pn[(size_t)(2 * q) * HDIM];
            nn.y = (_Float16)pn[(size_t)(2 * q + 1) * HDIM];
            z.x  = (_Float16)pz[(size_t)(2 * q) * HDIM];
            z.y  = (_Float16)pz[(size_t)(2 * q + 1) * HDIM];
            w2r[q] = r; w2n[q] = nn; w2z[q] = z;
        }
        #pragma unroll
        for (int q = 0; q < KPT / 2; ++q)
            asm volatile("" : "+v"(w2r[q]), "+v"(w2n[q]), "+v"(w2z[q]));
    }

    const size_t bb32 = (size_t)b * HDIM;
    unsigned long long* hTb = hT + bb32;
    unsigned long long* uTb = uT + bb32;
    const size_t gs = (size_t)M * HDIM;

    for (int tt = 0; tt < nt; ++tt) {
        const int t = t0 + tt;

        // xp prefetch (issued before polls; independent)
        float xr = 0.f, xnn = 0.f, xz = 0.f;
        const size_t rb = ((size_t)tt * BATCH + b) * HDIM;
        if (tid < COLS) {
            xr  = xp[rb + n];
            xnn = xp[gs + rb + n];
            xz  = xp[2 * gs + rb + n];
        }

        // ---- acquire h: element tid (own k-slot) + element n (own column) ----
        float hv, hcv = 0.f;
        if (t == 0) {
            hv = state[bb32 + tid];
            if (tid < COLS) hcv = state[bb32 + n];
        } else {
            unsigned long long v;
            do { v = loadt(hTb + tid); } while ((unsigned)(v >> 32) != (unsigned)t);
            hv = __uint_as_float((unsigned)v);
            if (tid < COLS) {
                do { v = loadt(hTb + n); } while ((unsigned)(v >> 32) != (unsigned)t);
                hcv = __uint_as_float((unsigned)v);
            }
        }

        // wave-local stage (wave j writes exactly the range it reads)
        hlds[tid] = (_Float16)hv;
        asm volatile("s_waitcnt lgkmcnt(0)" ::: "memory");
        __builtin_amdgcn_sched_barrier(0);

        // ---- R partials over own k-range (broadcast reads, conflict-free) ----
        {
            float aR = 0.f;
            const half8v* hp = (const half8v*)&hlds[j * KPT];
            #pragma unroll
            for (int q = 0; q < KPT / 8; ++q) {
                half8v h8 = hp[q];
                half2v p0 = {h8[0], h8[1]}, p1 = {h8[2], h8[3]};
                half2v p2 = {h8[4], h8[5]}, p3 = {h8[6], h8[7]};
                aR = dot2h(p0, w2r[4 * q + 0], aR);
                aR = dot2h(p1, w2r[4 * q + 1], aR);
                aR = dot2h(p2, w2r[4 * q + 2], aR);
                aR = dot2h(p3, w2r[4 * q + 3], aR);
            }
            redR[j][c] = aR;
        }
        __syncthreads();                               // barrier A

        // ---- wave 0: reduce, u = h*sigmoid, publish tagged u ----
        if (tid < COLS) {
            float sR = 0.f;
            #pragma unroll
            for (int jj = 0; jj < SLICES; ++jj) sR += redR[jj][c];
            float R = 1.f / (1.f + __expf(-(xr + sR)));
            storet(uTb + n, hcv * R, (unsigned)(t + 1));
        }

        // ---- all waves poll own u k-slot, stage wave-locally ----
        {
            unsigned long long v;
            do { v = loadt(uTb + tid); } while ((unsigned)(v >> 32) != (unsigned)(t + 1));
            ulds[tid] = (_Float16)__uint_as_float((unsigned)v);
        }
        asm volatile("s_waitcnt lgkmcnt(0)" ::: "memory");
        __builtin_amdgcn_sched_barrier(0);

        // ---- N,Z partials ----
        {
            float aN = 0.f, aZ = 0.f;
            const half8v* up = (const half8v*)&ulds[j * KPT];
            #pragma unroll
            for (int q = 0; q < KPT / 8; ++q) {
                half8v u8 = up[q];
                half2v p0 = {u8[0], u8[1]}, p1 = {u8[2], u8[3]};
                half2v p2 = {u8[4], u8[5]}, p3 = {u8[6], u8[7]};
                aN = dot2h(p0, w2n[4 * q + 0], aN);
                aZ = dot2h(p0, w2z[4 * q + 0], aZ);
                aN = dot2h(p1, w2n[4 * q + 1], aN);
                aZ = dot2h(p1, w2z[4 * q + 1], aZ);
                aN = dot2h(p2, w2n[4 * q + 2], aN);
                aZ = dot2h(p2, w2z[4 * q + 2], aZ);
                aN = dot2h(p3, w2n[4 * q + 3], aN);
                aZ = dot2h(p3, w2z[4 * q + 3], aZ);
            }
            redN[j][c] = aN;
            redZ[j][c] = aZ;
        }
        __syncthreads();                               // barrier B

        // ---- wave 0: h_new, publish tagged h + output ----
        if (tid < COLS) {
            float sN = 0.f, sZ = 0.f;
            #pragma unroll
            for (int jj = 0; jj < SLICES; ++jj) { sN += redN[jj][c]; sZ += redZ[jj][c]; }
            float e  = __expf(2.f * (xnn + sN));
            float Hc = 1.f - 2.f / (e + 1.f);          // tanh
            float Z  = 1.f / (1.f + __expf(-(xz + sZ)));
            float hnew = Z * hcv + (1.f - Z) * Hc;
            __builtin_nontemporal_store(hnew, out + (size_t)t * BATCH * HDIM + bb32 + n);
            storet(hTb + n, hnew, (unsigned)(t + 1));
            if (t == T_STEPS - 1)
                out[(size_t)T_STEPS * BATCH * HDIM + bb32 + n] = hnew;
        }
    }
}

extern "C" void kernel_launch(void* const* d_in, const int* in_sizes, int n_in,
                              void* d_out, int out_size, void* d_ws, size_t ws_size,
                              hipStream_t stream) {
    const float* inputs   = (const float*)d_in[0];
    const float* state    = (const float*)d_in[1];
    const float* W_reset  = (const float*)d_in[2];
    const float* b_reset  = (const float*)d_in[3];
    const float* W_net    = (const float*)d_in[4];
    const float* b_net    = (const float*)d_in[5];
    const float* W_update = (const float*)d_in[6];
    const float* b_update = (const float*)d_in[7];
    float* out = (float*)d_out;

    // tail: tagged h + tagged u = 2 * 32*512*8 B = 256 KB
    const size_t tail_bytes = 2ull * BATCH * HDIM * 8;
    size_t tail_base = (ws_size - tail_bytes) & ~(size_t)255;
    char* base = (char*)d_ws;
    float* xp = (float*)base;
    unsigned long long* hT = (unsigned long long*)(base + tail_base);
    unsigned long long* uT = hT + (size_t)BATCH * HDIM;

    const size_t per_t = 3ull * BATCH * HDIM * sizeof(float);
    int C = (int)(tail_base / per_t);
    if (C > T_STEPS) C = T_STEPS;
    C &= ~1;
    if (C < 2) C = 2;

    // tags must be != any step index at call start (0xFFFFFFFF); also wipes
    // stale tags from previous graph replays -> deterministic.
    hipMemsetAsync(hT, 0xFF, tail_bytes, stream);

    for (int t0 = 0; t0 < T_STEPS; t0 += C) {
        const int nt = (T_STEPS - t0 < C) ? (T_STEPS - t0) : C;
        const int M  = nt * BATCH;

        dim3 g1(HDIM / 64, M / 64, 3);
        xproj_gemm<<<g1, 256, 0, stream>>>(inputs + (size_t)t0 * BATCH * VDIM,
                                           W_reset, b_reset,
                                           W_net,   b_net,
                                           W_update, b_update,
                                           xp, M);

        gru_scan3<<<BATCH * SLICES, 512, 0, stream>>>(
            xp,
            W_reset  + (size_t)VDIM * HDIM,
            W_net    + (size_t)VDIM * HDIM,
            W_update + (size_t)VDIM * HDIM,
            state, out, hT, uT, t0, nt, M);
    }
}